// Round 6
// baseline (404.424 us; speedup 1.0000x reference)
//
#include <hip/hip_runtime.h>
#include <hip/hip_bf16.h>
#include <math.h>

// N_IN=32, N_OUT=31, H=128, npts=65536.
// Augmented propagation: X_{-1} = [I_31 | x] (32x32, LDS, diag static),
// X_l (128x32): Z = W_l @ X_{l-1}; X_l = [D*Z[:,:31] | tanh(Z[:,31]+b)].
// All layers via MFMA 16x16x32 bf16. 256-thread blocks (4 waves);
// wave q owns m-tiles {q, q+4} (rows 16q+r16, 16q+64+r16) -> B-frags shared
// across the 2 m-tiles (halves LDS reads). PB=2 points/pass, ping-pong XT,
// 4 barriers/pass, y prefetched a pass ahead. 40.8KB LDS -> 4 blocks/CU.

using short8 = __attribute__((ext_vector_type(8))) short;
using f32x4  = __attribute__((ext_vector_type(4))) float;

#define PB 2
#define PPB 16
#define NP (PPB / PB)  // 8 passes
#define ST 136         // XT row stride (272 B: 16B-aligned, avoids pow2 banks)
#define SIN 40         // Xin row stride (80 B)

__device__ __forceinline__ float fast_tanh(float z) {
    float e = __expf(2.0f * z);
    return 1.0f - 2.0f * __builtin_amdgcn_rcpf(e + 1.0f);
}
__device__ __forceinline__ unsigned pk2(float lo, float hi) {
    unsigned r;
    asm("v_cvt_pk_bf16_f32 %0, %1, %2" : "=v"(r) : "v"(lo), "v"(hi));
    return r;
}
__device__ __forceinline__ float bf2f(ushort u) {
    union { unsigned u; float f; } c; c.u = ((unsigned)u) << 16; return c.f;
}
__device__ __forceinline__ ushort f2bf1(float f) {
    union { float f; unsigned u; } v; v.f = f;
    unsigned r = v.u + 0x7fffu + ((v.u >> 16) & 1u);
    return (ushort)(r >> 16);
}
__device__ __forceinline__ short8 pack8f(const float* s) {
    union { unsigned u[4]; short8 v; } r;
    #pragma unroll
    for (int qq = 0; qq < 4; ++qq) r.u[qq] = pk2(s[2 * qq], s[2 * qq + 1]);
    return r.v;
}
__device__ __forceinline__ short8 load_row8(const float* p) {
    float tmp[8];
    const float4* p4 = reinterpret_cast<const float4*>(p);
    float4 q0 = p4[0], q1 = p4[1];
    tmp[0]=q0.x; tmp[1]=q0.y; tmp[2]=q0.z; tmp[3]=q0.w;
    tmp[4]=q1.x; tmp[5]=q1.y; tmp[6]=q1.z; tmp[7]=q1.w;
    return pack8f(tmp);
}

__global__ void __launch_bounds__(256, 4)
node_mfma2(const float* __restrict__ tptr,
           const float* __restrict__ y,
           const float* __restrict__ W0, const float* __restrict__ b0,
           const float* __restrict__ W1, const float* __restrict__ b1,
           const float* __restrict__ W2, const float* __restrict__ b2,
           const float* __restrict__ W3, const float* __restrict__ b3,
           float* __restrict__ out, float* __restrict__ jac, int npts) {
    __shared__ __align__(16) ushort XT[2][PB][32][ST];   // [buf][pt][col][row]
    __shared__ __align__(16) ushort Xin[PB][32][SIN];    // X_{-1}: [pt][col][row]
    __shared__ __align__(16) ushort bbf[3][128];         // b0,b1,b2 bf16
    __shared__ __align__(16) ushort b3bf[32];

    const int tid  = threadIdx.x;
    const int w    = tid >> 6;    // 0..3
    const int lane = tid & 63;
    const int r16  = lane & 15;
    const int g    = lane >> 4;
    const int q    = w;           // m-tile pair {q, q+4}

    // ---- A-fragments (register-resident weights) ----
    short8 aW0[2];       // W0 rows for mt 0/1, K=32 (1 kc)
    short8 aW[2][2][4];  // [layer][mt][kc] for W1, W2
    #pragma unroll
    for (int mt = 0; mt < 2; ++mt) {
        const int row = 16 * q + 64 * mt + r16;
        aW0[mt] = load_row8(W0 + row * 32 + g * 8);
        #pragma unroll
        for (int kc = 0; kc < 4; ++kc) {
            aW[0][mt][kc] = load_row8(W1 + row * 128 + kc * 32 + g * 8);
            aW[1][mt][kc] = load_row8(W2 + row * 128 + kc * 32 + g * 8);
        }
    }
    // L3: wave -> (pt3 = w>>1, mt3 = w&1); rows padded to 32 with zeros
    const int pt3 = w >> 1, mt3 = w & 1;
    const int r3 = 16 * mt3 + r16;
    short8 aW3[4];
    #pragma unroll
    for (int kc = 0; kc < 4; ++kc) {
        if (r3 < 31) aW3[kc] = load_row8(W3 + r3 * 128 + kc * 32 + g * 8);
        else { short8 z = {0,0,0,0,0,0,0,0}; aW3[kc] = z; }
    }

    // ---- LDS init: biases, Xin zero + diag ----
    for (int e = tid; e < 384; e += 256) {
        int L = e >> 7, i = e & 127;
        const float* bp = (L == 0) ? b0 : (L == 1) ? b1 : b2;
        bbf[L][i] = f2bf1(bp[i]);
    }
    if (tid < 32) b3bf[tid] = (tid < 31) ? f2bf1(b3[tid]) : (ushort)0;
    {
        uint* xz = reinterpret_cast<uint*>(&Xin[0][0][0]);
        for (int e = tid; e < PB * 32 * SIN / 2; e += 256) xz[e] = 0;
    }
    __syncthreads();
    if (tid < PB * 31) {
        int pt = tid / 31, c = tid % 31;
        Xin[pt][c][c] = 0x3F80;  // bf16 1.0
    }

    const float force = sinf(tptr[0]);

    // ---- y prefetch (pass 0) + initial Xin col 31 ----
    const bool act = tid < PB * 32;
    const int pl0 = tid >> 5, c0 = tid & 31;
    float pf = 0.0f;
    if (act && c0 < 31) pf = y[(size_t)(blockIdx.x * PPB + pl0) * 31 + c0];
    if (act) Xin[pl0][31][c0] = f2bf1(c0 < 31 ? pf : force);
    __syncthreads();

    // ---- shared epilogue: Z-acc -> X' (tanh col + D-scaled cols) ----
    auto epi = [&](f32x4 a0, f32x4 a1, int mt, const ushort* bL, ushort* dst) {
        const int row0 = 16 * q + 64 * mt;
        uint2 bq = *reinterpret_cast<const uint2*>(&bL[row0 + 4 * g]);
        const ushort* bqs = reinterpret_cast<const ushort*>(&bq);
        float va[4], vb[4];
        #pragma unroll
        for (int reg = 0; reg < 4; ++reg) {
            float tv = fast_tanh(a1[reg] + bf2f(bqs[reg]));
            float d  = 1.0f - tv * tv;
            float dd = __shfl(d, lane | 15, 64);
            va[reg] = dd * a0[reg];
            vb[reg] = (r16 == 15) ? tv : dd * a1[reg];
        }
        uint2 pa, pb;
        pa.x = pk2(va[0], va[1]); pa.y = pk2(va[2], va[3]);
        pb.x = pk2(vb[0], vb[1]); pb.y = pk2(vb[2], vb[3]);
        *reinterpret_cast<uint2*>(&dst[r16 * ST + row0 + 4 * g])        = pa;
        *reinterpret_cast<uint2*>(&dst[(16 + r16) * ST + row0 + 4 * g]) = pb;
    };

    for (int pass = 0; pass < NP; ++pass) {
        const int pbase = blockIdx.x * PPB + pass * PB;

        // issue y prefetch for next pass (consumed mid-pass)
        if (act && c0 < 31 && pass + 1 < NP)
            pf = y[(size_t)(pbase + PB + pl0) * 31 + c0];

        // ---- layer 0: Z0 = W0 @ [I|x]; -> XT[0] ----
        #pragma unroll
        for (int pt = 0; pt < PB; ++pt) {
            const ushort* src = &Xin[pt][0][0];
            short8 bf0 = *reinterpret_cast<const short8*>(&src[r16 * SIN + g * 8]);
            short8 bf1 = *reinterpret_cast<const short8*>(&src[(16 + r16) * SIN + g * 8]);
            f32x4 a00 = {0.f,0.f,0.f,0.f}, a01 = {0.f,0.f,0.f,0.f};
            f32x4 a10 = {0.f,0.f,0.f,0.f}, a11 = {0.f,0.f,0.f,0.f};
            __builtin_amdgcn_s_setprio(1);
            a00 = __builtin_amdgcn_mfma_f32_16x16x32_bf16(aW0[0], bf0, a00, 0, 0, 0);
            a01 = __builtin_amdgcn_mfma_f32_16x16x32_bf16(aW0[0], bf1, a01, 0, 0, 0);
            a10 = __builtin_amdgcn_mfma_f32_16x16x32_bf16(aW0[1], bf0, a10, 0, 0, 0);
            a11 = __builtin_amdgcn_mfma_f32_16x16x32_bf16(aW0[1], bf1, a11, 0, 0, 0);
            __builtin_amdgcn_s_setprio(0);
            epi(a00, a01, 0, bbf[0], &XT[0][pt][0][0]);
            epi(a10, a11, 1, bbf[0], &XT[0][pt][0][0]);
        }
        __syncthreads();  // [A] X0 ready

        // ---- layers 1, 2 (ping-pong) ----
        #pragma unroll
        for (int L = 0; L < 2; ++L) {
            #pragma unroll
            for (int pt = 0; pt < PB; ++pt) {
                f32x4 acc[2][2] = {{{0.f,0.f,0.f,0.f},{0.f,0.f,0.f,0.f}},
                                   {{0.f,0.f,0.f,0.f},{0.f,0.f,0.f,0.f}}};
                const ushort* src = &XT[L][pt][0][0];
                __builtin_amdgcn_s_setprio(1);
                #pragma unroll
                for (int kc = 0; kc < 4; ++kc) {
                    short8 bf0 = *reinterpret_cast<const short8*>(&src[r16 * ST + kc * 32 + g * 8]);
                    short8 bf1 = *reinterpret_cast<const short8*>(&src[(16 + r16) * ST + kc * 32 + g * 8]);
                    acc[0][0] = __builtin_amdgcn_mfma_f32_16x16x32_bf16(aW[L][0][kc], bf0, acc[0][0], 0, 0, 0);
                    acc[0][1] = __builtin_amdgcn_mfma_f32_16x16x32_bf16(aW[L][0][kc], bf1, acc[0][1], 0, 0, 0);
                    acc[1][0] = __builtin_amdgcn_mfma_f32_16x16x32_bf16(aW[L][1][kc], bf0, acc[1][0], 0, 0, 0);
                    acc[1][1] = __builtin_amdgcn_mfma_f32_16x16x32_bf16(aW[L][1][kc], bf1, acc[1][1], 0, 0, 0);
                }
                __builtin_amdgcn_s_setprio(0);
                ushort* dst = &XT[1 - L][pt][0][0];
                epi(acc[0][0], acc[0][1], 0, bbf[L + 1], dst);
                epi(acc[1][0], acc[1][1], 1, bbf[L + 1], dst);
            }
            __syncthreads();  // [B]/[C]
            if (L == 0 && act)  // Xin col31 for next pass (L0 reads long done)
                Xin[pl0][31][c0] = f2bf1(c0 < 31 ? pf : force);
        }

        // ---- layer 3: this wave does (pt3, mt3); X2 in XT[0] ----
        {
            const ushort* src = &XT[0][pt3][0][0];
            f32x4 ca = {0.f,0.f,0.f,0.f}, cb = {0.f,0.f,0.f,0.f};
            __builtin_amdgcn_s_setprio(1);
            #pragma unroll
            for (int kc = 0; kc < 4; ++kc) {
                short8 bf0 = *reinterpret_cast<const short8*>(&src[r16 * ST + kc * 32 + g * 8]);
                short8 bf1 = *reinterpret_cast<const short8*>(&src[(16 + r16) * ST + kc * 32 + g * 8]);
                ca = __builtin_amdgcn_mfma_f32_16x16x32_bf16(aW3[kc], bf0, ca, 0, 0, 0);
                cb = __builtin_amdgcn_mfma_f32_16x16x32_bf16(aW3[kc], bf1, cb, 0, 0, 0);
            }
            __builtin_amdgcn_s_setprio(0);
            const size_t p = (size_t)(pbase + pt3);
            if ((int)p < npts) {
                #pragma unroll
                for (int reg = 0; reg < 4; ++reg) {
                    const int o = 16 * mt3 + 4 * g + reg;
                    if (o < 31) {
                        jac[(p * 31 + o) * 31 + r16] = ca[reg];
                        if (r16 < 15)       jac[(p * 31 + o) * 31 + 16 + r16] = cb[reg];
                        else if (r16 == 15) out[p * 31 + o] = cb[reg] + bf2f(b3bf[o]);
                    }
                }
            }
        }
        __syncthreads();  // [E] XT[0] reads done; next pass may overwrite
    }
}

extern "C" void kernel_launch(void* const* d_in, const int* in_sizes, int n_in,
                              void* d_out, int out_size, void* d_ws, size_t ws_size,
                              hipStream_t stream) {
    const float* t  = (const float*)d_in[0];
    const float* y  = (const float*)d_in[1];
    const float* W0 = (const float*)d_in[2];
    const float* b0 = (const float*)d_in[3];
    const float* W1 = (const float*)d_in[4];
    const float* b1 = (const float*)d_in[5];
    const float* W2 = (const float*)d_in[6];
    const float* b2 = (const float*)d_in[7];
    const float* W3 = (const float*)d_in[8];
    const float* b3 = (const float*)d_in[9];

    const int npts = in_sizes[1] / 31;  // 65536
    float* out = (float*)d_out;
    float* jac = out + (size_t)npts * 31;

    const int blocks = (npts + PPB - 1) / PPB;  // 4096
    node_mfma2<<<blocks, 256, 0, stream>>>(t, y, W0, b0, W1, b1, W2, b2, W3, b3,
                                           out, jac, npts);
}